// Round 1
// baseline (161.613 us; speedup 1.0000x reference)
//
#include <hip/hip_runtime.h>
#include <math.h>

#define B 2
#define T 2048
#define D 512
#define KW 64        // attention window
#define SQRT_D_INV 0.044194173824159216f   // 1/sqrt(512)

// ---------------------------------------------------------------------------
// K1: q[b,t,d] = gelu_exact(conv1d(x, w, pad=1) + bias)   layout (B, T, D)
// ---------------------------------------------------------------------------
__global__ __launch_bounds__(256) void k_conv_gelu(
    const float* __restrict__ x, const float* __restrict__ w,
    const float* __restrict__ bias, float* __restrict__ q) {
  int bt = blockIdx.x;                 // 0 .. B*T-1
  int b = bt / T, t = bt - b * T;
  const float xm1 = (t > 0)     ? x[b * T + t - 1] : 0.f;
  const float x0  =               x[b * T + t];
  const float xp1 = (t < T - 1) ? x[b * T + t + 1] : 0.f;
  for (int d = threadIdx.x; d < D; d += 256) {
    float v = xm1 * w[d * 3 + 0] + x0 * w[d * 3 + 1] + xp1 * w[d * 3 + 2] + bias[d];
    // exact gelu: v * 0.5 * (1 + erf(v/sqrt(2)))
    float g = 0.5f * v * (1.f + erff(v * 0.70710678118654752f));
    q[(size_t)bt * D + d] = g;
  }
}

// ---------------------------------------------------------------------------
// K2: energy[b,t,k] = (1/sqrt(D)) * dot_c(q[b,t,:], q[b,t-63+k,:]),
//     attn = softmax_k(energy).  Block = (b, 16-t tile), 256 threads.
//     Window rows staged in LDS in 8 chunks of 64 channels.
//     Row stride 68 floats: rows 16B-aligned (272B) -> ds_read_b128 friendly.
// ---------------------------------------------------------------------------
#define TT2 16
#define ROWS2 (TT2 + KW - 1)   // 79
#define PAD2 68

__global__ __launch_bounds__(256) void k_energy_softmax(
    const float* __restrict__ q, float* __restrict__ attn) {
  __shared__ float s_win[ROWS2 * PAD2];   // 79*68*4 = 21.5 KB

  int blk = blockIdx.x;                   // 0 .. B*(T/TT2)-1 = 255
  int b = blk / (T / TT2);
  int t0 = (blk - b * (T / TT2)) * TT2;
  int tid = threadIdx.x;
  int lane = tid & 63;                    // k index
  int wave = tid >> 6;                    // 0..3

  float acc[TT2 / 4];
#pragma unroll
  for (int p = 0; p < TT2 / 4; ++p) acc[p] = 0.f;

  const size_t qb = (size_t)b * T * D;

  for (int cc = 0; cc < D / 64; ++cc) {
    // stage 79 rows x 64 channels (zero-fill t' < 0)
    for (int idx = tid; idx < ROWS2 * 64; idx += 256) {
      int r = idx >> 6, c = idx & 63;
      int tp = t0 - (KW - 1) + r;
      s_win[r * PAD2 + c] =
          (tp >= 0) ? q[qb + (size_t)tp * D + cc * 64 + c] : 0.f;
    }
    __syncthreads();

#pragma unroll
    for (int p = 0; p < TT2 / 4; ++p) {
      int tl = p * 4 + wave;                       // local t
      const float* rq = &s_win[(tl + KW - 1) * PAD2];  // query row (wave-uniform)
      const float* rk = &s_win[(tl + lane) * PAD2];    // key row (per-lane)
      float a = acc[p];
#pragma unroll
      for (int c = 0; c < 64; ++c) a += rq[c] * rk[c];
      acc[p] = a;
    }
    __syncthreads();
  }

  // softmax over k (= lane) within each wave, per local t
#pragma unroll
  for (int p = 0; p < TT2 / 4; ++p) {
    int tl = p * 4 + wave;
    float e = acc[p] * SQRT_D_INV;
    float m = e;
    for (int off = 32; off >= 1; off >>= 1) m = fmaxf(m, __shfl_xor(m, off, 64));
    float pe = expf(e - m);
    float s = pe;
    for (int off = 32; off >= 1; off >>= 1) s += __shfl_xor(s, off, 64);
    attn[((size_t)b * T + t0 + tl) * KW + lane] = pe / s;
  }
}

// ---------------------------------------------------------------------------
// K3: context[b,c,t] = tanh(gate) * sum_k attn[b,t,k] * q[b, t-63+k, c]
//     Block = (b, 64-t tile, 64-c tile), 256 threads.
//     lane = local t (coalesced output), wave+4j = local c (16-way reg block).
//     Pad 65 here: lane-varying ROW index -> stride 1 mod 32 banks (free).
// ---------------------------------------------------------------------------
#define TT3 64
#define ROWS3 (TT3 + KW - 1)   // 127
#define PAD3 65

__global__ __launch_bounds__(256) void k_context(
    const float* __restrict__ q, const float* __restrict__ attn,
    const float* __restrict__ gate, float* __restrict__ out) {
  __shared__ float s_q[ROWS3 * PAD3];   // 127*65*4 = 33.0 KB
  __shared__ float s_a[TT3 * PAD3];     // 64*65*4  = 16.6 KB

  int blk = blockIdx.x;                 // 0 .. 511
  int nct = (T / TT3) * (D / 64);       // 32*8 = 256 per batch
  int b = blk / nct;
  int rem = blk - b * nct;
  int t0 = (rem / (D / 64)) * TT3;
  int c0 = (rem - (rem / (D / 64)) * (D / 64)) * 64;
  int tid = threadIdx.x;
  int lane = tid & 63;                  // local t
  int wave = tid >> 6;                  // c = wave + 4*j

  const size_t qb = (size_t)b * T * D;
  for (int idx = tid; idx < ROWS3 * 64; idx += 256) {
    int r = idx >> 6, c = idx & 63;
    int tp = t0 - (KW - 1) + r;
    s_q[r * PAD3 + c] = (tp >= 0) ? q[qb + (size_t)tp * D + c0 + c] : 0.f;
  }
  for (int idx = tid; idx < TT3 * KW; idx += 256) {
    int tt = idx >> 6, k = idx & 63;
    s_a[tt * PAD3 + k] = attn[((size_t)b * T + t0 + tt) * KW + k];
  }
  __syncthreads();

  const float tg = tanhf(gate[0]);
  float acc[16];
#pragma unroll
  for (int j = 0; j < 16; ++j) acc[j] = 0.f;

#pragma unroll 1
  for (int k = 0; k < KW; ++k) {
    float a = s_a[lane * PAD3 + k];
    const float* rp = &s_q[(lane + k) * PAD3];
#pragma unroll
    for (int j = 0; j < 16; ++j) acc[j] += a * rp[wave + 4 * j];
  }

#pragma unroll
  for (int j = 0; j < 16; ++j) {
    int c = c0 + wave + 4 * j;
    out[((size_t)b * D + c) * T + t0 + lane] = acc[j] * tg;
  }
}

// ---------------------------------------------------------------------------
extern "C" void kernel_launch(void* const* d_in, const int* in_sizes, int n_in,
                              void* d_out, int out_size, void* d_ws, size_t ws_size,
                              hipStream_t stream) {
  const float* x      = (const float*)d_in[0];   // (B,1,T)
  const float* conv_w = (const float*)d_in[1];   // (D,1,3)
  const float* conv_b = (const float*)d_in[2];   // (D,)
  const float* gate   = (const float*)d_in[3];   // scalar
  float* out = (float*)d_out;                    // (B,D,T)

  // workspace: q (B*T*D fp32, 8 MB) then attn (B*T*K fp32, 1 MB)
  float* q_ws    = (float*)d_ws;
  float* attn_ws = q_ws + (size_t)B * T * D;

  k_conv_gelu<<<B * T, 256, 0, stream>>>(x, conv_w, conv_b, q_ws);
  k_energy_softmax<<<B * (T / TT2), 256, 0, stream>>>(q_ws, attn_ws);
  k_context<<<B * (T / TT3) * (D / 64), 256, 0, stream>>>(q_ws, attn_ws, gate, out);
}

// Round 2
// 117.240 us; speedup vs baseline: 1.3785x; 1.3785x over previous
//
#include <hip/hip_runtime.h>
#include <math.h>

#define B 2
#define T 2048
#define D 512
#define KW 64
#define SCALE 0.044194173824159216f   // 1/sqrt(512)

typedef __attribute__((ext_vector_type(8))) short short8;   // 8 bf16 (4 VGPRs)
typedef __attribute__((ext_vector_type(4))) float f32x4;    // MFMA C/D

// float -> bf16 (RNE)
__device__ __forceinline__ ushort f2bf(float f) {
  union { float f; unsigned u; } v; v.f = f;
  unsigned r = v.u + 0x7fffu + ((v.u >> 16) & 1u);
  return (ushort)(r >> 16);
}

__device__ __forceinline__ float conv_gelu_val(
    const float* __restrict__ x, const float* __restrict__ w,
    const float* __restrict__ bias, int b, int t, int c) {
  float xm1 = (t > 0)     ? x[b * T + t - 1] : 0.f;
  float x0  =               x[b * T + t];
  float xp1 = (t < T - 1) ? x[b * T + t + 1] : 0.f;
  float v = xm1 * w[c * 3] + x0 * w[c * 3 + 1] + xp1 * w[c * 3 + 2] + bias[c];
  return 0.5f * v * (1.f + erff(v * 0.70710678118654752f));
}

// ---------------------------------------------------------------------------
// K1: q (t-major, [b][t][c]) and qT (c-major, [b][c][t]) as bf16.
// Each thread writes one element of each copy; both stores coalesced.
// ---------------------------------------------------------------------------
__global__ __launch_bounds__(256) void k_conv(
    const float* __restrict__ x, const float* __restrict__ w,
    const float* __restrict__ bias, ushort* __restrict__ q,
    ushort* __restrict__ qT) {
  int i = blockIdx.x * 256 + threadIdx.x;        // [0, B*T*D)
  // t-major: i = (b*T + t)*D + c
  int c  = i & (D - 1);
  int t  = (i >> 9) & (T - 1);
  int b  = i >> 20;
  q[i] = f2bf(conv_gelu_val(x, w, bias, b, t, c));
  // c-major: i = (b*D + c)*T + t
  int t2 = i & (T - 1);
  int c2 = (i >> 11) & (D - 1);
  qT[i] = f2bf(conv_gelu_val(x, w, bias, b, t2, c2));
}

// ---------------------------------------------------------------------------
// K2 (fused): per 16-t tile (one wave):
//   E[m=t][n=j] = Q[16x512] * K'[512x80]   (5 j-chunks x 16 K-steps of MFMA)
//   band-masked softmax over j in registers (quad-group shfl reduce)
//   A'[m][j'] in LDS (bf16, j' = j+1 shift keeps context B-frags 16B-aligned)
//   C[m=t][n=c] = A'[16x96] * W[96x512]    (3 K-steps x 32 n-chunks)
// MFMA 16x16x32 bf16 layouts (guide §3, m89/m120-verified):
//   A[m=lane&15][k=quad*8+j], B[k=quad*8+j][n=lane&15],
//   C/D: col=lane&15, row=quad*4+reg.
// ---------------------------------------------------------------------------
__global__ __launch_bounds__(64) void k_attn(
    const ushort* __restrict__ q, const ushort* __restrict__ qT,
    const float* __restrict__ gate, float* __restrict__ out) {
  __shared__ alignas(16) ushort s_attn[16 * 96];

  int tile = blockIdx.x;                 // 0 .. B*T/16-1
  int b  = tile >> 7;                    // T/16 = 128 tiles per batch
  int t0 = (tile & 127) << 4;
  int lane = threadIdx.x;
  int n    = lane & 15;
  int quad = lane >> 4;

  const ushort* qb = q + (size_t)b * T * D;
  const short8 zero8 = {0, 0, 0, 0, 0, 0, 0, 0};

  // ---- energy GEMM: acc[jc] = E[:, jc*16 .. jc*16+15] -------------------
  f32x4 acc[5];
#pragma unroll
  for (int jc = 0; jc < 5; ++jc) acc[jc] = (f32x4){0.f, 0.f, 0.f, 0.f};

#pragma unroll 4
  for (int kc = 0; kc < 16; ++kc) {
    int cofs = kc * 32 + quad * 8;
    short8 afr = *(const short8*)(qb + (size_t)(t0 + n) * D + cofs);
#pragma unroll
    for (int jc = 0; jc < 5; ++jc) {
      int tp = t0 - (KW - 1) + jc * 16 + n;        // key row
      short8 bfr = (tp >= 0 && tp < T)
                       ? *(const short8*)(qb + (size_t)tp * D + cofs)
                       : zero8;
      acc[jc] = __builtin_amdgcn_mfma_f32_16x16x32_bf16(afr, bfr, acc[jc], 0, 0, 0);
    }
  }

  // ---- band-masked softmax over j (per row m = quad*4+r) ----------------
#pragma unroll
  for (int r = 0; r < 4; ++r) {
    int m = quad * 4 + r;
    float e[5];
    float mx = -1e30f;
#pragma unroll
    for (int jc = 0; jc < 5; ++jc) {
      int j = jc * 16 + n;
      bool valid = (j >= m) && (j <= m + (KW - 1));
      e[jc] = valid ? acc[jc][r] * SCALE : -1e30f;
      mx = fmaxf(mx, e[jc]);
    }
#pragma unroll
    for (int off = 1; off <= 8; off <<= 1) mx = fmaxf(mx, __shfl_xor(mx, off, 64));
    float p[5];
    float s = 0.f;
#pragma unroll
    for (int jc = 0; jc < 5; ++jc) {
      p[jc] = (e[jc] > -1e29f) ? __expf(e[jc] - mx) : 0.f;
      s += p[jc];
    }
#pragma unroll
    for (int off = 1; off <= 8; off <<= 1) s += __shfl_xor(s, off, 64);
    float inv = 1.f / s;
    // store A' row m: col j+1 = attn, cols {0, 81..95} = 0
#pragma unroll
    for (int jc = 0; jc < 5; ++jc) {
      int j = jc * 16 + n;
      s_attn[m * 96 + j + 1] = f2bf(p[jc] * inv);
    }
    int jp = (n == 0) ? 0 : (80 + n);
    s_attn[m * 96 + jp] = 0;
  }
  __syncthreads();   // single wave: just forces LDS write->read ordering

  // ---- context GEMM: C[m=t][n=c] = A' * W -------------------------------
  short8 afr2[3];
#pragma unroll
  for (int ks = 0; ks < 3; ++ks)
    afr2[ks] = *(const short8*)(s_attn + n * 96 + ks * 32 + quad * 8);

  const ushort* qTb = qT + (size_t)b * D * T;
  const float tg = tanhf(gate[0]);

#pragma unroll 4
  for (int nc = 0; nc < 32; ++nc) {
    int c = nc * 16 + n;
    f32x4 co = (f32x4){0.f, 0.f, 0.f, 0.f};
#pragma unroll
    for (int ks = 0; ks < 3; ++ks) {
      int tbase = t0 - KW + ks * 32 + quad * 8;    // t' for jj=0 (j' shift: t'=t0-64+k)
      short8 bfr = (tbase >= 0 && tbase < T)
                       ? *(const short8*)(qTb + (size_t)c * T + tbase)
                       : zero8;
      co = __builtin_amdgcn_mfma_f32_16x16x32_bf16(afr2[ks], bfr, co, 0, 0, 0);
    }
    f32x4 o;
    o[0] = co[0] * tg; o[1] = co[1] * tg; o[2] = co[2] * tg; o[3] = co[3] * tg;
    // rows t0+quad*4+{0..3} at col c -> contiguous float4 in (b,c,t) layout
    *(f32x4*)(out + ((size_t)b * D + c) * T + t0 + quad * 4) = o;
  }
}

// ---------------------------------------------------------------------------
extern "C" void kernel_launch(void* const* d_in, const int* in_sizes, int n_in,
                              void* d_out, int out_size, void* d_ws, size_t ws_size,
                              hipStream_t stream) {
  const float* x      = (const float*)d_in[0];   // (B,1,T)
  const float* conv_w = (const float*)d_in[1];   // (D,1,3)
  const float* conv_b = (const float*)d_in[2];   // (D,)
  const float* gate   = (const float*)d_in[3];   // scalar
  float* out = (float*)d_out;                    // (B,D,T)

  ushort* q_ws  = (ushort*)d_ws;                       // bf16, t-major, 4.19 MB
  ushort* qT_ws = q_ws + (size_t)B * T * D;            // bf16, c-major, 4.19 MB

  k_conv<<<(B * T * D) / 256, 256, 0, stream>>>(x, conv_w, conv_b, q_ws, qT_ws);
  k_attn<<<B * T / 16, 64, 0, stream>>>(q_ws, qT_ws, gate, out);
}

// Round 3
// 83.977 us; speedup vs baseline: 1.9245x; 1.3961x over previous
//
#include <hip/hip_runtime.h>
#include <math.h>

#define B 2
#define T 2048
#define D 512
#define KW 64
#define SCALE 0.044194173824159216f   // 1/sqrt(512)

typedef __attribute__((ext_vector_type(8))) short short8;   // 8 bf16 (4 VGPRs)
typedef __attribute__((ext_vector_type(4))) float f32x4;    // MFMA C/D

// float -> bf16 (RNE)
__device__ __forceinline__ ushort f2bf(float f) {
  union { float f; unsigned u; } v; v.f = f;
  unsigned r = v.u + 0x7fffu + ((v.u >> 16) & 1u);
  return (ushort)(r >> 16);
}

// ---------------------------------------------------------------------------
// K1: q (t-major) and qT (c-major) bf16; each gelu computed ONCE, transpose
// through padded LDS so both stores are coalesced. Block = 64t x 64c tile.
// ---------------------------------------------------------------------------
__global__ __launch_bounds__(256) void k_conv(
    const float* __restrict__ x, const float* __restrict__ w,
    const float* __restrict__ bias, ushort* __restrict__ q,
    ushort* __restrict__ qT) {
  __shared__ float s_tile[64 * 65];   // pad 65: both phases 2-way (free)

  int blk = blockIdx.x;               // B * 32 * 8 = 512 blocks
  int b   = blk >> 8;
  int rem = blk & 255;
  int t0  = (rem >> 3) << 6;
  int c0  = (rem & 7) << 6;
  int tid = threadIdx.x;

  // compute phase: thread = (lt, 16-c strip)
  int lt = tid >> 2;
  int cb = (tid & 3) << 4;
  int t = t0 + lt;
  float xm1 = (t > 0)     ? x[b * T + t - 1] : 0.f;
  float x0  =               x[b * T + t];
  float xp1 = (t < T - 1) ? x[b * T + t + 1] : 0.f;
#pragma unroll
  for (int e = 0; e < 16; ++e) {
    int c = c0 + cb + e;
    float v = xm1 * w[c * 3] + x0 * w[c * 3 + 1] + xp1 * w[c * 3 + 2] + bias[c];
    float g = 0.5f * v * (1.f + erff(v * 0.70710678118654752f));
    q[((size_t)b * T + t) * D + c] = f2bf(g);
    s_tile[lt * 65 + cb + e] = g;
  }
  __syncthreads();

  // transpose phase: thread = (lc, 16-t strip)
  int lc = tid >> 2;
  int tb = (tid & 3) << 4;
#pragma unroll
  for (int e = 0; e < 16; ++e) {
    int ltt = tb + e;
    qT[((size_t)b * D + c0 + lc) * T + t0 + ltt] = f2bf(s_tile[ltt * 65 + lc]);
  }
}

// ---------------------------------------------------------------------------
// K2 (fused, 4 waves per 16-t tile):
//   energy: wave w covers channels [w*128, w*128+128) -> partial E[16x80],
//           LDS-reduce, wave 0: band-masked softmax -> A' bf16 in LDS
//   context: wave w covers c-chunks [w*8, w*8+8)
// MFMA 16x16x32 bf16: A[m=lane&15][k=quad*8+j], B[k][n=lane&15],
//                     C/D col=lane&15, row=quad*4+reg.
// XCD swizzle: blk -> tile = (blk%8)*32 + blk/8 keeps each XCD on a
// contiguous 512-t range (window working set ~1.2 MB -> L2-resident).
// ---------------------------------------------------------------------------
__global__ __launch_bounds__(256) void k_attn(
    const ushort* __restrict__ q, const ushort* __restrict__ qT,
    const float* __restrict__ gate, float* __restrict__ out) {
  __shared__ float s_E[3 * 5 * 4 * 64];            // 15360 B partial slabs
  __shared__ alignas(16) ushort s_attn[16 * 96];   // 3072 B

  int blk  = blockIdx.x;                 // 256 blocks
  int tile = (blk & 7) * 32 + (blk >> 3);
  int b  = tile >> 7;
  int t0 = (tile & 127) << 4;
  int tid  = threadIdx.x;
  int wv   = tid >> 6;                   // 0..3
  int lane = tid & 63;
  int n    = lane & 15;
  int quad = lane >> 4;

  const ushort* qb = q + (size_t)b * T * D;
  const short8 zero8 = {0, 0, 0, 0, 0, 0, 0, 0};

  // ---- energy partial GEMM: this wave's 128 channels ---------------------
  f32x4 acc[5];
#pragma unroll
  for (int jc = 0; jc < 5; ++jc) acc[jc] = (f32x4){0.f, 0.f, 0.f, 0.f};

#pragma unroll
  for (int i = 0; i < 4; ++i) {
    int cofs = (wv * 4 + i) * 32 + quad * 8;
    short8 afr = *(const short8*)(qb + (size_t)(t0 + n) * D + cofs);
#pragma unroll
    for (int jc = 0; jc < 5; ++jc) {
      int tp = t0 - (KW - 1) + jc * 16 + n;
      short8 bfr = (tp >= 0 && tp < T)
                       ? *(const short8*)(qb + (size_t)tp * D + cofs)
                       : zero8;
      acc[jc] = __builtin_amdgcn_mfma_f32_16x16x32_bf16(afr, bfr, acc[jc], 0, 0, 0);
    }
  }

  // ---- cross-wave reduce (waves 1-3 write slabs, wave 0 sums) ------------
  if (wv) {
#pragma unroll
    for (int jc = 0; jc < 5; ++jc)
#pragma unroll
      for (int r = 0; r < 4; ++r)
        s_E[(((wv - 1) * 5 + jc) * 4 + r) * 64 + lane] = acc[jc][r];
  }
  __syncthreads();

  if (wv == 0) {
#pragma unroll
    for (int ww = 0; ww < 3; ++ww)
#pragma unroll
      for (int jc = 0; jc < 5; ++jc)
#pragma unroll
        for (int r = 0; r < 4; ++r)
          acc[jc][r] += s_E[((ww * 5 + jc) * 4 + r) * 64 + lane];

    // ---- band-masked softmax over j, rows m = quad*4+r -------------------
#pragma unroll
    for (int r = 0; r < 4; ++r) {
      int m = quad * 4 + r;
      float e[5];
      float mx = -1e30f;
#pragma unroll
      for (int jc = 0; jc < 5; ++jc) {
        int j = jc * 16 + n;
        bool valid = (j >= m) && (j <= m + (KW - 1));
        e[jc] = valid ? acc[jc][r] * SCALE : -1e30f;
        mx = fmaxf(mx, e[jc]);
      }
#pragma unroll
      for (int off = 1; off <= 8; off <<= 1) mx = fmaxf(mx, __shfl_xor(mx, off, 64));
      float p[5];
      float s = 0.f;
#pragma unroll
      for (int jc = 0; jc < 5; ++jc) {
        p[jc] = (e[jc] > -1e29f) ? __expf(e[jc] - mx) : 0.f;
        s += p[jc];
      }
#pragma unroll
      for (int off = 1; off <= 8; off <<= 1) s += __shfl_xor(s, off, 64);
      float inv = 1.f / s;
      // A' row m: col j+1 = attn (j'-shift keeps B-frags 16B-aligned),
      // cols {0, 81..95} = 0
#pragma unroll
      for (int jc = 0; jc < 5; ++jc) {
        int j = jc * 16 + n;
        s_attn[m * 96 + j + 1] = f2bf(p[jc] * inv);
      }
      int jp = (n == 0) ? 0 : (80 + n);
      s_attn[m * 96 + jp] = 0;
    }
  }
  __syncthreads();

  // ---- context GEMM: wave w handles c-chunks w*8 .. w*8+7 ----------------
  short8 afr2[3];
#pragma unroll
  for (int ks = 0; ks < 3; ++ks)
    afr2[ks] = *(const short8*)(s_attn + n * 96 + ks * 32 + quad * 8);

  const ushort* qTb = qT + (size_t)b * D * T;
  const float tg = tanhf(gate[0]);

#pragma unroll
  for (int ncl = 0; ncl < 8; ++ncl) {
    int c = (wv * 8 + ncl) * 16 + n;
    f32x4 co = (f32x4){0.f, 0.f, 0.f, 0.f};
#pragma unroll
    for (int ks = 0; ks < 3; ++ks) {
      int tbase = t0 - KW + ks * 32 + quad * 8;   // t' = t0-64+j'
      short8 bfr = (tbase >= 0 && tbase < T)
                       ? *(const short8*)(qTb + (size_t)c * T + tbase)
                       : zero8;
      co = __builtin_amdgcn_mfma_f32_16x16x32_bf16(afr2[ks], bfr, co, 0, 0, 0);
    }
    f32x4 o;
    o[0] = co[0] * tg; o[1] = co[1] * tg; o[2] = co[2] * tg; o[3] = co[3] * tg;
    *(f32x4*)(out + ((size_t)b * D + c) * T + t0 + quad * 4) = o;
  }
}

// ---------------------------------------------------------------------------
extern "C" void kernel_launch(void* const* d_in, const int* in_sizes, int n_in,
                              void* d_out, int out_size, void* d_ws, size_t ws_size,
                              hipStream_t stream) {
  const float* x      = (const float*)d_in[0];   // (B,1,T)
  const float* conv_w = (const float*)d_in[1];   // (D,1,3)
  const float* conv_b = (const float*)d_in[2];   // (D,)
  const float* gate   = (const float*)d_in[3];   // scalar
  float* out = (float*)d_out;                    // (B,D,T)

  ushort* q_ws  = (ushort*)d_ws;                 // bf16 t-major, 4.19 MB
  ushort* qT_ws = q_ws + (size_t)B * T * D;      // bf16 c-major, 4.19 MB

  k_conv<<<B * 256, 256, 0, stream>>>(x, conv_w, conv_b, q_ws, qT_ws);
  k_attn<<<B * T / 16, 256, 0, stream>>>(q_ws, qT_ws, gate, out);
}

// Round 4
// 79.674 us; speedup vs baseline: 2.0284x; 1.0540x over previous
//
#include <hip/hip_runtime.h>
#include <math.h>

#define B 2
#define T 2048
#define D 512
#define KW 64
#define SCALE 0.044194173824159216f   // 1/sqrt(512)

// padded layouts: 64 zero rows/elems in front, 16 behind
#define RQ (64 + T + 16)     // q_pad rows per batch (t index = row - 64)
#define TTP (64 + T + 16)    // qT_pad elems per (b,c) row (t index = elem - 64)

typedef __attribute__((ext_vector_type(8))) short short8;   // 8 bf16 (4 VGPRs)
typedef __attribute__((ext_vector_type(4))) float f32x4;    // MFMA C/D

// float -> bf16 (RNE)
__device__ __forceinline__ ushort f2bf(float f) {
  union { float f; unsigned u; } v; v.f = f;
  unsigned r = v.u + 0x7fffu + ((v.u >> 16) & 1u);
  return (ushort)(r >> 16);
}

// ---------------------------------------------------------------------------
// K1: q_pad (t-major) and qT_pad (c-major) bf16, gelu computed once,
// transpose through padded LDS. Blocks 0..511: 64t x 64c tiles.
// Blocks 512..519: zero the pad regions (re-poisoned to 0xAA every launch).
// ---------------------------------------------------------------------------
__global__ __launch_bounds__(256) void k_conv(
    const float* __restrict__ x, const float* __restrict__ w,
    const float* __restrict__ bias, ushort* __restrict__ q,
    ushort* __restrict__ qT) {
  int blk = blockIdx.x;
  int tid = threadIdx.x;

  if (blk >= 512) {            // ---- pad zeroing: 20480 x 16B stores ----
    int ztid = (blk - 512) * 256 + tid;          // 0..2047
    const uint4 z = {0u, 0u, 0u, 0u};
    for (int task = ztid; task < 20480; task += 2048) {
      size_t e;
      if (task < 8192) {                         // q front: 64 rows x 512
        int b = task >> 12, i = task & 4095;
        e = (size_t)b * RQ * D + (size_t)i * 8;
      } else if (task < 10240) {                 // q back: 16 rows x 512
        int idx = task - 8192;
        int b = idx >> 10, i = idx & 1023;
        e = (size_t)b * RQ * D + (size_t)(64 + T) * D + (size_t)i * 8;
      } else if (task < 18432) {                 // qT front: 64 per row
        int idx = task - 10240;
        int r = idx >> 3, i = idx & 7;
        e = (size_t)r * TTP + (size_t)i * 8;
        *(uint4*)(qT + e) = z;
        continue;
      } else {                                   // qT back: 16 per row
        int idx = task - 18432;
        int r = idx >> 1, i = idx & 1;
        e = (size_t)r * TTP + 64 + T + (size_t)i * 8;
        *(uint4*)(qT + e) = z;
        continue;
      }
      *(uint4*)(q + e) = z;
    }
    return;
  }

  __shared__ float s_tile[64 * 65];   // pad 65: both phases 2-way (free)
  int b   = blk >> 8;
  int rem = blk & 255;
  int t0  = (rem >> 3) << 6;
  int c0  = (rem & 7) << 6;

  // compute phase: thread = (lt, 16-c strip)
  int lt = tid >> 2;
  int cb = (tid & 3) << 4;
  int t = t0 + lt;
  float xm1 = (t > 0)     ? x[b * T + t - 1] : 0.f;
  float x0  =               x[b * T + t];
  float xp1 = (t < T - 1) ? x[b * T + t + 1] : 0.f;
#pragma unroll
  for (int e = 0; e < 16; ++e) {
    int c = c0 + cb + e;
    float v = xm1 * w[c * 3] + x0 * w[c * 3 + 1] + xp1 * w[c * 3 + 2] + bias[c];
    float g = 0.5f * v * (1.f + erff(v * 0.70710678118654752f));
    q[((size_t)b * RQ + 64 + t) * D + c] = f2bf(g);
    s_tile[lt * 65 + cb + e] = g;
  }
  __syncthreads();

  // transpose phase: thread = (lc, 16-t strip)
  int lc = tid >> 2;
  int tb = (tid & 3) << 4;
#pragma unroll
  for (int e = 0; e < 16; ++e) {
    int ltt = tb + e;
    qT[((size_t)b * D + c0 + lc) * TTP + 64 + t0 + ltt] =
        f2bf(s_tile[ltt * 65 + lc]);
  }
}

// ---------------------------------------------------------------------------
// K2 (fused, 4 waves per 16-t tile). All loads unconditional (padded bufs)
// and batch-preloaded into register arrays before the MFMA loops.
//   energy: wave w = channels [w*128, w*128+128) -> partial E[16x80];
//           slabs to LDS, ONE barrier, every wave sums all partials and
//           does softmax redundantly -> private A' copy (no 2nd barrier).
//   context: wave w = c-chunks [w*8, w*8+8).
// MFMA 16x16x32 bf16: A[m=lane&15][k=quad*8+j], B[k][n=lane&15],
//                     C/D col=lane&15, row=quad*4+reg.
// ---------------------------------------------------------------------------
__global__ __launch_bounds__(256) void k_attn(
    const ushort* __restrict__ q, const ushort* __restrict__ qT,
    const float* __restrict__ gate, float* __restrict__ out) {
  __shared__ float s_E[4 * 5 * 4 * 64];                 // 20480 B
  __shared__ alignas(16) ushort s_attn[4][16 * 96];     // 12288 B

  int blk  = blockIdx.x;                 // 256 blocks
  int tile = (blk & 7) * 32 + (blk >> 3);   // XCD swizzle: contiguous t per XCD
  int b  = tile >> 7;
  int t0 = (tile & 127) << 4;
  int tid  = threadIdx.x;
  int wv   = tid >> 6;
  int lane = tid & 63;
  int n    = lane & 15;
  int quad = lane >> 4;

  const ushort* qb = q + (size_t)b * RQ * D + (size_t)64 * D;  // row = t
  const ushort* qTb = qT + (size_t)b * D * TTP;                // elem = t + 64

  // ---- energy: preload all fragments, then MFMA -------------------------
  short8 afr[4], bfr[4][5];
#pragma unroll
  for (int i = 0; i < 4; ++i) {
    int cofs = (wv * 4 + i) * 32 + quad * 8;
    afr[i] = *(const short8*)(qb + (size_t)(t0 + n) * D + cofs);
#pragma unroll
    for (int jc = 0; jc < 5; ++jc) {
      int tp = t0 - (KW - 1) + jc * 16 + n;       // in [-63, T], padded: valid
      bfr[i][jc] = *(const short8*)(qb + (ptrdiff_t)tp * D + cofs);
    }
  }

  f32x4 acc[5];
#pragma unroll
  for (int jc = 0; jc < 5; ++jc) acc[jc] = (f32x4){0.f, 0.f, 0.f, 0.f};
#pragma unroll
  for (int i = 0; i < 4; ++i)
#pragma unroll
    for (int jc = 0; jc < 5; ++jc)
      acc[jc] = __builtin_amdgcn_mfma_f32_16x16x32_bf16(afr[i], bfr[i][jc],
                                                        acc[jc], 0, 0, 0);

  // ---- cross-wave reduce: every wave writes its slab, sums the others ----
#pragma unroll
  for (int jc = 0; jc < 5; ++jc)
#pragma unroll
    for (int r = 0; r < 4; ++r)
      s_E[((wv * 5 + jc) * 4 + r) * 64 + lane] = acc[jc][r];
  __syncthreads();

#pragma unroll
  for (int ww = 0; ww < 4; ++ww) {
    if (ww == wv) continue;
#pragma unroll
    for (int jc = 0; jc < 5; ++jc)
#pragma unroll
      for (int r = 0; r < 4; ++r)
        acc[jc][r] += s_E[((ww * 5 + jc) * 4 + r) * 64 + lane];
  }

  // ---- band-masked softmax (redundant per wave), private A' copy ---------
  ushort* sa = s_attn[wv];
#pragma unroll
  for (int r = 0; r < 4; ++r) {
    int m = quad * 4 + r;
    float e[5];
    float mx = -1e30f;
#pragma unroll
    for (int jc = 0; jc < 5; ++jc) {
      int j = jc * 16 + n;
      bool valid = (j >= m) && (j <= m + (KW - 1));
      e[jc] = valid ? acc[jc][r] * SCALE : -1e30f;
      mx = fmaxf(mx, e[jc]);
    }
#pragma unroll
    for (int off = 1; off <= 8; off <<= 1) mx = fmaxf(mx, __shfl_xor(mx, off, 64));
    float p[5];
    float s = 0.f;
#pragma unroll
    for (int jc = 0; jc < 5; ++jc) {
      p[jc] = (e[jc] > -1e29f) ? __expf(e[jc] - mx) : 0.f;
      s += p[jc];
    }
#pragma unroll
    for (int off = 1; off <= 8; off <<= 1) s += __shfl_xor(s, off, 64);
    float inv = 1.f / s;
    // A' row m: col j+1 = attn (j' shift keeps B-frags 16B-aligned),
    // cols {0, 81..95} = 0
#pragma unroll
    for (int jc = 0; jc < 5; ++jc) {
      int j = jc * 16 + n;
      sa[m * 96 + j + 1] = f2bf(p[jc] * inv);
    }
    int jp = (n == 0) ? 0 : (80 + n);
    sa[m * 96 + jp] = 0;
  }
  // same-wave LDS write->read: compiler orders via lgkmcnt, no barrier

  // ---- context: preload all fragments, then MFMA ------------------------
  short8 afr2[3];
#pragma unroll
  for (int ks = 0; ks < 3; ++ks)
    afr2[ks] = *(const short8*)(sa + n * 96 + ks * 32 + quad * 8);

  short8 bfr2[8][3];
#pragma unroll
  for (int ncl = 0; ncl < 8; ++ncl) {
    int c = (wv * 8 + ncl) * 16 + n;
#pragma unroll
    for (int ks = 0; ks < 3; ++ks) {
      // t' = t0-64+j', pad offset +64 -> elem = t0 + ks*32 + quad*8
      bfr2[ncl][ks] = *(const short8*)(qTb + (size_t)c * TTP + t0 + ks * 32 + quad * 8);
    }
  }

  const float tg = tanhf(gate[0]);
#pragma unroll
  for (int ncl = 0; ncl < 8; ++ncl) {
    int c = (wv * 8 + ncl) * 16 + n;
    f32x4 co = (f32x4){0.f, 0.f, 0.f, 0.f};
#pragma unroll
    for (int ks = 0; ks < 3; ++ks)
      co = __builtin_amdgcn_mfma_f32_16x16x32_bf16(afr2[ks], bfr2[ncl][ks],
                                                   co, 0, 0, 0);
    f32x4 o;
    o[0] = co[0] * tg; o[1] = co[1] * tg; o[2] = co[2] * tg; o[3] = co[3] * tg;
    *(f32x4*)(out + ((size_t)b * D + c) * T + t0 + quad * 4) = o;
  }
}

// ---------------------------------------------------------------------------
extern "C" void kernel_launch(void* const* d_in, const int* in_sizes, int n_in,
                              void* d_out, int out_size, void* d_ws, size_t ws_size,
                              hipStream_t stream) {
  const float* x      = (const float*)d_in[0];   // (B,1,T)
  const float* conv_w = (const float*)d_in[1];   // (D,1,3)
  const float* conv_b = (const float*)d_in[2];   // (D,)
  const float* gate   = (const float*)d_in[3];   // scalar
  float* out = (float*)d_out;                    // (B,D,T)

  ushort* q_ws  = (ushort*)d_ws;                     // bf16 t-major padded, 4.36 MB
  ushort* qT_ws = q_ws + (size_t)B * RQ * D;         // bf16 c-major padded, 4.36 MB

  k_conv<<<520, 256, 0, stream>>>(x, conv_w, conv_b, q_ws, qT_ws);
  k_attn<<<B * T / 16, 256, 0, stream>>>(q_ws, qT_ws, gate, out);
}

// Round 5
// 77.884 us; speedup vs baseline: 2.0750x; 1.0230x over previous
//
#include <hip/hip_runtime.h>
#include <math.h>

#define B 2
#define T 2048
#define D 512
#define KW 64
#define SCALE 0.044194173824159216f   // 1/sqrt(512)

// padded layouts: 64 zero rows/elems in front, 16 behind
#define RQ (64 + T + 16)     // q_pad rows per batch (t index = row - 64)
#define TTP (64 + T + 16)    // qT_pad elems per (b,c) row (t index = elem - 64)

typedef __attribute__((ext_vector_type(8))) short short8;   // 8 bf16 (4 VGPRs)
typedef __attribute__((ext_vector_type(4))) float f32x4;    // MFMA C/D

// float -> bf16 (RNE)
__device__ __forceinline__ ushort f2bf(float f) {
  union { float f; unsigned u; } v; v.f = f;
  unsigned r = v.u + 0x7fffu + ((v.u >> 16) & 1u);
  return (ushort)(r >> 16);
}

// ---------------------------------------------------------------------------
// K1: q_pad (t-major) and qT_pad (c-major) bf16; gelu once; LDS transpose;
// VECTORIZED short8 stores (2 per phase instead of 16 scalar 2B stores).
// XCD-matched mapping: blk&7 = xcd -> (b, 512-t range) identical to k_attn's
// consumer swizzle, so attn reads hit the local XCD's L2.
// Blocks 512..519 zero the pad regions (ws re-poisoned every launch).
// ---------------------------------------------------------------------------
__global__ __launch_bounds__(256) void k_conv(
    const float* __restrict__ x, const float* __restrict__ w,
    const float* __restrict__ bias, ushort* __restrict__ q,
    ushort* __restrict__ qT) {
  int blk = blockIdx.x;
  int tid = threadIdx.x;

  if (blk >= 512) {            // ---- pad zeroing: 20480 x 16B stores ----
    int ztid = (blk - 512) * 256 + tid;          // 0..2047
    const uint4 z = {0u, 0u, 0u, 0u};
    for (int task = ztid; task < 20480; task += 2048) {
      size_t e;
      if (task < 8192) {                         // q front: 64 rows x 512
        int b = task >> 12, i = task & 4095;
        e = (size_t)b * RQ * D + (size_t)i * 8;
      } else if (task < 10240) {                 // q back: 16 rows x 512
        int idx = task - 8192;
        int b = idx >> 10, i = idx & 1023;
        e = (size_t)b * RQ * D + (size_t)(64 + T) * D + (size_t)i * 8;
      } else if (task < 18432) {                 // qT front: 64 per row
        int idx = task - 10240;
        int r = idx >> 3, i = idx & 7;
        e = (size_t)r * TTP + (size_t)i * 8;
        *(uint4*)(qT + e) = z;
        continue;
      } else {                                   // qT back: 16 per row
        int idx = task - 18432;
        int r = idx >> 1, i = idx & 1;
        e = (size_t)r * TTP + 64 + T + (size_t)i * 8;
        *(uint4*)(qT + e) = z;
        continue;
      }
      *(uint4*)(q + e) = z;
    }
    return;
  }

  __shared__ float s_tile[64 * 65];   // pad 65: both phases ~2-way (free)

  // XCD-matched tile mapping
  int xcd = blk & 7;
  int i   = blk >> 3;                  // 0..63 within xcd
  int b   = xcd >> 2;
  int t0  = (xcd & 3) * 512 + (i >> 3) * 64;
  int c0  = (i & 7) * 64;

  // compute phase: thread = (lt = tid>>2, 16-c strip cb = (tid&3)*16)
  int lt = tid >> 2;
  int cb = (tid & 3) << 4;
  int t = t0 + lt;
  float xm1 = (t > 0)     ? x[b * T + t - 1] : 0.f;
  float x0  =               x[b * T + t];
  float xp1 = (t < T - 1) ? x[b * T + t + 1] : 0.f;
  short8 h0, h1;
#pragma unroll
  for (int e = 0; e < 16; ++e) {
    int c = c0 + cb + e;
    float v = xm1 * w[c * 3] + x0 * w[c * 3 + 1] + xp1 * w[c * 3 + 2] + bias[c];
    float g = 0.5f * v * (1.f + erff(v * 0.70710678118654752f));
    s_tile[lt * 65 + cb + e] = g;
    if (e < 8) h0[e] = (short)f2bf(g); else h1[e - 8] = (short)f2bf(g);
  }
  {
    ushort* qp = q + ((size_t)b * RQ + 64 + t) * D + c0 + cb;
    *(short8*)qp = h0;
    *(short8*)(qp + 8) = h1;
  }
  __syncthreads();

  // transpose phase: thread = (lc = tid>>2, 16-t strip tb = (tid&3)*16)
  int lc = tid >> 2;
  int tb = (tid & 3) << 4;
  short8 v0, v1;
#pragma unroll
  for (int e = 0; e < 8; ++e)
    v0[e] = (short)f2bf(s_tile[(tb + e) * 65 + lc]);
#pragma unroll
  for (int e = 0; e < 8; ++e)
    v1[e] = (short)f2bf(s_tile[(tb + 8 + e) * 65 + lc]);
  {
    ushort* qp = qT + ((size_t)b * D + c0 + lc) * TTP + 64 + t0 + tb;
    *(short8*)qp = v0;
    *(short8*)(qp + 8) = v1;
  }
}

// ---------------------------------------------------------------------------
// K2 (fused, 4 waves per 16-t tile). ALL 48 global fragment loads issued up
// front (before the barrier) -> single memory-latency epoch; launch_bounds
// (256,1): 1 block/CU anyway, so fat VGPR use is free.
//   energy: wave w = channels [w*128, w*128+128) -> partial E[16x80];
//           slabs to LDS, ONE barrier, redundant reduce+softmax per wave ->
//           private A' copy (no 2nd barrier).
//   context: wave w = c-chunks [w*8, w*8+8).
// MFMA 16x16x32 bf16: A[m=lane&15][k=quad*8+j], B[k][n=lane&15],
//                     C/D col=lane&15, row=quad*4+reg.
// ---------------------------------------------------------------------------
__global__ __launch_bounds__(256, 1) void k_attn(
    const ushort* __restrict__ q, const ushort* __restrict__ qT,
    const float* __restrict__ gate, float* __restrict__ out) {
  __shared__ float s_E[4 * 5 * 4 * 64];                 // 20480 B
  __shared__ alignas(16) ushort s_attn[4][16 * 96];     // 12288 B

  int blk  = blockIdx.x;                 // 256 blocks = 1/CU
  int tile = (blk & 7) * 32 + (blk >> 3);   // XCD k -> contiguous 512-t range
  int b  = tile >> 7;
  int t0 = (tile & 127) << 4;
  int tid  = threadIdx.x;
  int wv   = tid >> 6;
  int lane = tid & 63;
  int n    = lane & 15;
  int quad = lane >> 4;

  const ushort* qb = q + (size_t)b * RQ * D + (size_t)64 * D;  // row = t
  const ushort* qTb = qT + (size_t)b * D * TTP;                // elem = t + 64

  // ---- issue ALL global loads (energy + context frags) ------------------
  short8 afr[4], bfr[4][5];
#pragma unroll
  for (int i = 0; i < 4; ++i) {
    int cofs = (wv * 4 + i) * 32 + quad * 8;
    afr[i] = *(const short8*)(qb + (size_t)(t0 + n) * D + cofs);
#pragma unroll
    for (int jc = 0; jc < 5; ++jc) {
      int tp = t0 - (KW - 1) + jc * 16 + n;       // in [-63, T+15], pad-valid
      bfr[i][jc] = *(const short8*)(qb + (ptrdiff_t)tp * D + cofs);
    }
  }
  short8 bfr2[8][3];
#pragma unroll
  for (int ncl = 0; ncl < 8; ++ncl) {
    int c = (wv * 8 + ncl) * 16 + n;
#pragma unroll
    for (int ks = 0; ks < 3; ++ks)
      // t' = t0-64+j', pad +64 -> elem = t0 + ks*32 + quad*8
      bfr2[ncl][ks] =
          *(const short8*)(qTb + (size_t)c * TTP + t0 + ks * 32 + quad * 8);
  }

  // ---- energy partial GEMM ----------------------------------------------
  f32x4 acc[5];
#pragma unroll
  for (int jc = 0; jc < 5; ++jc) acc[jc] = (f32x4){0.f, 0.f, 0.f, 0.f};
#pragma unroll
  for (int i = 0; i < 4; ++i)
#pragma unroll
    for (int jc = 0; jc < 5; ++jc)
      acc[jc] = __builtin_amdgcn_mfma_f32_16x16x32_bf16(afr[i], bfr[i][jc],
                                                        acc[jc], 0, 0, 0);

  // ---- cross-wave reduce: every wave writes its slab, sums the others ----
#pragma unroll
  for (int jc = 0; jc < 5; ++jc)
#pragma unroll
    for (int r = 0; r < 4; ++r)
      s_E[((wv * 5 + jc) * 4 + r) * 64 + lane] = acc[jc][r];
  __syncthreads();

#pragma unroll
  for (int ww = 0; ww < 4; ++ww) {
    if (ww == wv) continue;
#pragma unroll
    for (int jc = 0; jc < 5; ++jc)
#pragma unroll
      for (int r = 0; r < 4; ++r)
        acc[jc][r] += s_E[((ww * 5 + jc) * 4 + r) * 64 + lane];
  }

  // ---- band-masked softmax (redundant per wave), private A' copy ---------
  ushort* sa = s_attn[wv];
#pragma unroll
  for (int r = 0; r < 4; ++r) {
    int m = quad * 4 + r;
    float e[5];
    float mx = -1e30f;
#pragma unroll
    for (int jc = 0; jc < 5; ++jc) {
      int j = jc * 16 + n;
      bool valid = (j >= m) && (j <= m + (KW - 1));
      e[jc] = valid ? acc[jc][r] * SCALE : -1e30f;
      mx = fmaxf(mx, e[jc]);
    }
#pragma unroll
    for (int off = 1; off <= 8; off <<= 1) mx = fmaxf(mx, __shfl_xor(mx, off, 64));
    float p[5];
    float s = 0.f;
#pragma unroll
    for (int jc = 0; jc < 5; ++jc) {
      p[jc] = (e[jc] > -1e29f) ? __expf(e[jc] - mx) : 0.f;
      s += p[jc];
    }
#pragma unroll
    for (int off = 1; off <= 8; off <<= 1) s += __shfl_xor(s, off, 64);
    float inv = 1.f / s;
    // A' row m: col j+1 = attn (j' shift keeps B-frags 16B-aligned),
    // cols {0, 81..95} = 0
#pragma unroll
    for (int jc = 0; jc < 5; ++jc) {
      int j = jc * 16 + n;
      sa[m * 96 + j + 1] = f2bf(p[jc] * inv);
    }
    int jp = (n == 0) ? 0 : (80 + n);
    sa[m * 96 + jp] = 0;
  }
  // same-wave LDS write->read: ordered via lgkmcnt, no barrier needed

  // ---- context GEMM (B-frags already resident) --------------------------
  short8 afr2[3];
#pragma unroll
  for (int ks = 0; ks < 3; ++ks)
    afr2[ks] = *(const short8*)(sa + n * 96 + ks * 32 + quad * 8);

  const float tg = tanhf(gate[0]);
#pragma unroll
  for (int ncl = 0; ncl < 8; ++ncl) {
    int c = (wv * 8 + ncl) * 16 + n;
    f32x4 co = (f32x4){0.f, 0.f, 0.f, 0.f};
#pragma unroll
    for (int ks = 0; ks < 3; ++ks)
      co = __builtin_amdgcn_mfma_f32_16x16x32_bf16(afr2[ks], bfr2[ncl][ks],
                                                   co, 0, 0, 0);
    f32x4 o;
    o[0] = co[0] * tg; o[1] = co[1] * tg; o[2] = co[2] * tg; o[3] = co[3] * tg;
    *(f32x4*)(out + ((size_t)b * D + c) * T + t0 + quad * 4) = o;
  }
}

// ---------------------------------------------------------------------------
extern "C" void kernel_launch(void* const* d_in, const int* in_sizes, int n_in,
                              void* d_out, int out_size, void* d_ws, size_t ws_size,
                              hipStream_t stream) {
  const float* x      = (const float*)d_in[0];   // (B,1,T)
  const float* conv_w = (const float*)d_in[1];   // (D,1,3)
  const float* conv_b = (const float*)d_in[2];   // (D,)
  const float* gate   = (const float*)d_in[3];   // scalar
  float* out = (float*)d_out;                    // (B,D,T)

  ushort* q_ws  = (ushort*)d_ws;                 // bf16 t-major padded, 4.36 MB
  ushort* qT_ws = q_ws + (size_t)B * RQ * D;     // bf16 c-major padded, 4.36 MB

  k_conv<<<520, 256, 0, stream>>>(x, conv_w, conv_b, q_ws, qT_ws);
  k_attn<<<B * T / 16, 256, 0, stream>>>(q_ws, qT_ws, gate, out);
}

// Round 6
// 75.621 us; speedup vs baseline: 2.1371x; 1.0299x over previous
//
#include <hip/hip_runtime.h>
#include <math.h>

#define B 2
#define T 2048
#define D 512
#define KW 64
#define SCALE 0.044194173824159216f   // 1/sqrt(512)

// padded layouts: 64 zero rows/elems in front, 16 behind
#define RQ (64 + T + 16)     // q_pad rows per batch (t index = row - 64)
#define TTP (64 + T + 16)    // qT_pad elems per (b,c) row (t index = elem - 64)

typedef __attribute__((ext_vector_type(8))) short short8;   // 8 bf16 (4 VGPRs)
typedef __attribute__((ext_vector_type(4))) float f32x4;    // MFMA C/D

// float -> bf16 (RNE)
__device__ __forceinline__ ushort f2bf(float f) {
  union { float f; unsigned u; } v; v.f = f;
  unsigned r = v.u + 0x7fffu + ((v.u >> 16) & 1u);
  return (ushort)(r >> 16);
}

// tanh-form gelu: 0.5v(1+tanh(0.79788456(v+0.044715v^3)))
//              == v - v/(1+exp2(2.885390082*u)),  u = 0.79788456v + 0.035677408v^3
// |approx - exact| < ~1e-3 on the value range here; bf16 rounding (7.8e-3)
// dominates. ~9 VALU (2 transcendental-rate) vs erff's ~25.
__device__ __forceinline__ float gelu_fast(float v) {
  float v2 = v * v;
  float u  = fmaf(v2 * v, 0.03567740814f, 0.7978845608f * v);
  float e  = __builtin_amdgcn_exp2f(2.885390082f * u);
  float r  = __builtin_amdgcn_rcpf(1.f + e);
  return fmaf(-v, r, v);
}

// ---------------------------------------------------------------------------
// K1: q_pad (t-major) and qT_pad (c-major) bf16; gelu once; LDS transpose;
// short8 vector stores; float4-vectorized w/bias loads.
// XCD-matched mapping: blk&7 = xcd -> (b, 512-t range) identical to k_attn's
// consumer swizzle, so attn reads hit the local XCD's L2.
// Blocks 512..519 zero the pad regions (ws re-poisoned every launch).
// ---------------------------------------------------------------------------
__global__ __launch_bounds__(256) void k_conv(
    const float* __restrict__ x, const float* __restrict__ w,
    const float* __restrict__ bias, ushort* __restrict__ q,
    ushort* __restrict__ qT) {
  int blk = blockIdx.x;
  int tid = threadIdx.x;

  if (blk >= 512) {            // ---- pad zeroing: 20480 x 16B stores ----
    int ztid = (blk - 512) * 256 + tid;          // 0..2047
    const uint4 z = {0u, 0u, 0u, 0u};
    for (int task = ztid; task < 20480; task += 2048) {
      size_t e;
      if (task < 8192) {                         // q front: 64 rows x 512
        int b = task >> 12, i = task & 4095;
        e = (size_t)b * RQ * D + (size_t)i * 8;
      } else if (task < 10240) {                 // q back: 16 rows x 512
        int idx = task - 8192;
        int b = idx >> 10, i = idx & 1023;
        e = (size_t)b * RQ * D + (size_t)(64 + T) * D + (size_t)i * 8;
      } else if (task < 18432) {                 // qT front: 64 per row
        int idx = task - 10240;
        int r = idx >> 3, i = idx & 7;
        e = (size_t)r * TTP + (size_t)i * 8;
        *(uint4*)(qT + e) = z;
        continue;
      } else {                                   // qT back: 16 per row
        int idx = task - 18432;
        int r = idx >> 1, i = idx & 1;
        e = (size_t)r * TTP + 64 + T + (size_t)i * 8;
        *(uint4*)(qT + e) = z;
        continue;
      }
      *(uint4*)(q + e) = z;
    }
    return;
  }

  __shared__ float s_tile[64 * 65];   // pad 65: both phases ~2-way (free)

  // XCD-matched tile mapping
  int xcd = blk & 7;
  int i   = blk >> 3;                  // 0..63 within xcd
  int b   = xcd >> 2;
  int t0  = (xcd & 3) * 512 + (i >> 3) * 64;
  int c0  = (i & 7) * 64;

  // compute phase: thread = (lt = tid>>2, 16-c strip cb = (tid&3)*16)
  int lt = tid >> 2;
  int cb = (tid & 3) << 4;
  int t = t0 + lt;
  float xm1 = (t > 0)     ? x[b * T + t - 1] : 0.f;
  float x0  =               x[b * T + t];
  float xp1 = (t < T - 1) ? x[b * T + t + 1] : 0.f;

  // vectorized weight/bias loads: 48 w floats (16B-aligned) + 16 bias
  float wf[48], bf[16];
#pragma unroll
  for (int v4 = 0; v4 < 12; ++v4)
    *(float4*)&wf[v4 * 4] = *(const float4*)(w + (size_t)(c0 + cb) * 3 + v4 * 4);
#pragma unroll
  for (int v4 = 0; v4 < 4; ++v4)
    *(float4*)&bf[v4 * 4] = *(const float4*)(bias + c0 + cb + v4 * 4);

  short8 h0, h1;
#pragma unroll
  for (int e = 0; e < 16; ++e) {
    float v = fmaf(xm1, wf[e * 3], fmaf(x0, wf[e * 3 + 1],
              fmaf(xp1, wf[e * 3 + 2], bf[e])));
    float g = gelu_fast(v);
    s_tile[lt * 65 + cb + e] = g;
    if (e < 8) h0[e] = (short)f2bf(g); else h1[e - 8] = (short)f2bf(g);
  }
  {
    ushort* qp = q + ((size_t)b * RQ + 64 + t) * D + c0 + cb;
    *(short8*)qp = h0;
    *(short8*)(qp + 8) = h1;
  }
  __syncthreads();

  // transpose phase: thread = (lc = tid>>2, 16-t strip tb = (tid&3)*16)
  int lc = tid >> 2;
  int tb = (tid & 3) << 4;
  short8 v0, v1;
#pragma unroll
  for (int e = 0; e < 8; ++e)
    v0[e] = (short)f2bf(s_tile[(tb + e) * 65 + lc]);
#pragma unroll
  for (int e = 0; e < 8; ++e)
    v1[e] = (short)f2bf(s_tile[(tb + 8 + e) * 65 + lc]);
  {
    ushort* qp = qT + ((size_t)b * D + c0 + lc) * TTP + 64 + t0 + tb;
    *(short8*)qp = v0;
    *(short8*)(qp + 8) = v1;
  }
}

// ---------------------------------------------------------------------------
// K2 (fused, 4 waves per 16-t tile). ALL 48 global fragment loads issued up
// front (single memory-latency epoch); launch_bounds(256,1): 1 block/CU.
//   energy: wave w = channels [w*128, w*128+128) -> partial E[16x80];
//           lane-major f32x4 slabs to LDS (b128 ops), ONE barrier,
//           redundant reduce+softmax per wave -> private A' copy.
//   context: wave w = c-chunks [w*8, w*8+8).
// MFMA 16x16x32 bf16: A[m=lane&15][k=quad*8+j], B[k][n=lane&15],
//                     C/D col=lane&15, row=quad*4+reg.
// ---------------------------------------------------------------------------
__global__ __launch_bounds__(256, 1) void k_attn(
    const ushort* __restrict__ q, const ushort* __restrict__ qT,
    const float* __restrict__ gate, float* __restrict__ out) {
  __shared__ alignas(16) f32x4 s_E[4 * 5 * 64];         // 20480 B, lane-major
  __shared__ alignas(16) ushort s_attn[4][16 * 96];     // 12288 B

  int blk  = blockIdx.x;                 // 256 blocks = 1/CU
  int tile = (blk & 7) * 32 + (blk >> 3);   // XCD k -> contiguous 512-t range
  int b  = tile >> 7;
  int t0 = (tile & 127) << 4;
  int tid  = threadIdx.x;
  int wv   = tid >> 6;
  int lane = tid & 63;
  int n    = lane & 15;
  int quad = lane >> 4;

  const ushort* qb = q + (size_t)b * RQ * D + (size_t)64 * D;  // row = t
  const ushort* qTb = qT + (size_t)b * D * TTP;                // elem = t + 64

  // ---- issue ALL global loads (energy + context frags) ------------------
  short8 afr[4], bfr[4][5];
#pragma unroll
  for (int i = 0; i < 4; ++i) {
    int cofs = (wv * 4 + i) * 32 + quad * 8;
    afr[i] = *(const short8*)(qb + (size_t)(t0 + n) * D + cofs);
#pragma unroll
    for (int jc = 0; jc < 5; ++jc) {
      int tp = t0 - (KW - 1) + jc * 16 + n;       // in [-63, T+15], pad-valid
      bfr[i][jc] = *(const short8*)(qb + (ptrdiff_t)tp * D + cofs);
    }
  }
  short8 bfr2[8][3];
#pragma unroll
  for (int ncl = 0; ncl < 8; ++ncl) {
    int c = (wv * 8 + ncl) * 16 + n;
#pragma unroll
    for (int ks = 0; ks < 3; ++ks)
      // t' = t0-64+j', pad +64 -> elem = t0 + ks*32 + quad*8
      bfr2[ncl][ks] =
          *(const short8*)(qTb + (size_t)c * TTP + t0 + ks * 32 + quad * 8);
  }

  // ---- energy partial GEMM ----------------------------------------------
  f32x4 acc[5];
#pragma unroll
  for (int jc = 0; jc < 5; ++jc) acc[jc] = (f32x4){0.f, 0.f, 0.f, 0.f};
#pragma unroll
  for (int i = 0; i < 4; ++i)
#pragma unroll
    for (int jc = 0; jc < 5; ++jc)
      acc[jc] = __builtin_amdgcn_mfma_f32_16x16x32_bf16(afr[i], bfr[i][jc],
                                                        acc[jc], 0, 0, 0);

  // ---- cross-wave reduce: lane-major f32x4 slabs (b128 LDS ops) ----------
#pragma unroll
  for (int jc = 0; jc < 5; ++jc)
    s_E[(wv * 5 + jc) * 64 + lane] = acc[jc];
  __syncthreads();

#pragma unroll
  for (int ww = 0; ww < 4; ++ww) {
    if (ww == wv) continue;
#pragma unroll
    for (int jc = 0; jc < 5; ++jc) {
      f32x4 v = s_E[(ww * 5 + jc) * 64 + lane];
      acc[jc][0] += v[0]; acc[jc][1] += v[1];
      acc[jc][2] += v[2]; acc[jc][3] += v[3];
    }
  }

  // ---- band-masked softmax (redundant per wave), private A' copy ---------
  ushort* sa = s_attn[wv];
#pragma unroll
  for (int r = 0; r < 4; ++r) {
    int m = quad * 4 + r;
    float e[5];
    float mx = -1e30f;
#pragma unroll
    for (int jc = 0; jc < 5; ++jc) {
      int j = jc * 16 + n;
      bool valid = (j >= m) && (j <= m + (KW - 1));
      e[jc] = valid ? acc[jc][r] * SCALE : -1e30f;
      mx = fmaxf(mx, e[jc]);
    }
#pragma unroll
    for (int off = 1; off <= 8; off <<= 1) mx = fmaxf(mx, __shfl_xor(mx, off, 64));
    float p[5];
    float s = 0.f;
#pragma unroll
    for (int jc = 0; jc < 5; ++jc) {
      p[jc] = (e[jc] > -1e29f) ? __expf(e[jc] - mx) : 0.f;
      s += p[jc];
    }
#pragma unroll
    for (int off = 1; off <= 8; off <<= 1) s += __shfl_xor(s, off, 64);
    float inv = 1.f / s;
    // A' row m: col j+1 = attn (j' shift keeps B-frags 16B-aligned),
    // cols {0, 81..95} = 0
#pragma unroll
    for (int jc = 0; jc < 5; ++jc) {
      int j = jc * 16 + n;
      sa[m * 96 + j + 1] = f2bf(p[jc] * inv);
    }
    int jp = (n == 0) ? 0 : (80 + n);
    sa[m * 96 + jp] = 0;
  }
  // same-wave LDS write->read: ordered via lgkmcnt, no barrier needed

  // ---- context GEMM (B-frags already resident) --------------------------
  short8 afr2[3];
#pragma unroll
  for (int ks = 0; ks < 3; ++ks)
    afr2[ks] = *(const short8*)(sa + n * 96 + ks * 32 + quad * 8);

  const float tg = tanhf(gate[0]);
#pragma unroll
  for (int ncl = 0; ncl < 8; ++ncl) {
    int c = (wv * 8 + ncl) * 16 + n;
    f32x4 co = (f32x4){0.f, 0.f, 0.f, 0.f};
#pragma unroll
    for (int ks = 0; ks < 3; ++ks)
      co = __builtin_amdgcn_mfma_f32_16x16x32_bf16(afr2[ks], bfr2[ncl][ks],
                                                   co, 0, 0, 0);
    f32x4 o;
    o[0] = co[0] * tg; o[1] = co[1] * tg; o[2] = co[2] * tg; o[3] = co[3] * tg;
    *(f32x4*)(out + ((size_t)b * D + c) * T + t0 + quad * 4) = o;
  }
}

// ---------------------------------------------------------------------------
extern "C" void kernel_launch(void* const* d_in, const int* in_sizes, int n_in,
                              void* d_out, int out_size, void* d_ws, size_t ws_size,
                              hipStream_t stream) {
  const float* x      = (const float*)d_in[0];   // (B,1,T)
  const float* conv_w = (const float*)d_in[1];   // (D,1,3)
  const float* conv_b = (const float*)d_in[2];   // (D,)
  const float* gate   = (const float*)d_in[3];   // scalar
  float* out = (float*)d_out;                    // (B,D,T)

  ushort* q_ws  = (ushort*)d_ws;                 // bf16 t-major padded, 4.36 MB
  ushort* qT_ws = q_ws + (size_t)B * RQ * D;     // bf16 c-major padded, 4.36 MB

  k_conv<<<520, 256, 0, stream>>>(x, conv_w, conv_b, q_ws, qT_ws);
  k_attn<<<B * T / 16, 256, 0, stream>>>(q_ws, qT_ws, gate, out);
}